// Round 19
// baseline (258.162 us; speedup 1.0000x reference)
//
#include <hip/hip_runtime.h>
#include <hip/hip_fp16.h>

#define S_LEN 512
#define B_DIM 1024
#define T_DIM 48
#define L2E 1.4426950408889634f
#define LN2 0.6931471805599453f

#define EXP2F(x) __builtin_amdgcn_exp2f(x)
#define LOG2F(x) __builtin_amdgcn_logf(x)

typedef _Float16 h2v __attribute__((ext_vector_type(2)));
typedef _Float16 r4  __attribute__((ext_vector_type(4)));
typedef float    f4  __attribute__((ext_vector_type(4)));

// v_mfma_f32_16x16x16_f16 : D(16x16 f32) = A(16x16 f16) x B(16x16 f16) + C
// Guarded so the HOST pass never sees the builtin (aux-target __has_builtin
// is false on host -- that was r18's compile failure).
__device__ __forceinline__ f4 MFMA16(r4 a, r4 b, f4 c) {
#if defined(__HIP_DEVICE_COMPILE__)
  return __builtin_amdgcn_mfma_f32_16x16x16f16(a, b, c, 0, 0, 0);
#else
  (void)a; (void)b; return c;
#endif
}

// packed f16 max (ROCm 7.2 lacks __hmax2)
__device__ __forceinline__ __half2 hmax2(__half2 a, __half2 b) {
  h2v r = __builtin_elementwise_max(__builtin_bit_cast(h2v, a),
                                    __builtin_bit_cast(h2v, b));
  return __builtin_bit_cast(__half2, r);
}
__device__ __forceinline__ __half2 bpick(__half2 src, int lane) {
  int s = __builtin_amdgcn_readlane(__builtin_bit_cast(int, src), lane);
  return __builtin_bit_cast(__half2, s);
}

template <int CTRL, int RMASK>
__device__ __forceinline__ float dppmovf(float v) {
  return __int_as_float(__builtin_amdgcn_update_dpp(
      __float_as_int(v), __float_as_int(v), CTRL, RMASK, 0xF, false));
}
template <int CTRL, int RMASK>
__device__ __forceinline__ float dppmaxf(float m) {
  return fmaxf(m, dppmovf<CTRL, RMASK>(m));
}
template <int CTRL, int RMASK>
__device__ __forceinline__ float dppaddf(float m) {
  return m + dppmovf<CTRL, RMASK>(m);
}
__device__ __forceinline__ float wave_max63(float m) {
  m = dppmaxf<0xB1, 0xF>(m);  m = dppmaxf<0x4E, 0xF>(m);
  m = dppmaxf<0x141, 0xF>(m); m = dppmaxf<0x140, 0xF>(m);
  m = dppmaxf<0x142, 0xA>(m); m = dppmaxf<0x143, 0xC>(m);
  return __int_as_float(__builtin_amdgcn_readlane(__float_as_int(m), 63));
}
__device__ __forceinline__ float wave_sum63(float m) {
  m = dppaddf<0xB1, 0xF>(m);  m = dppaddf<0x4E, 0xF>(m);
  m = dppaddf<0x141, 0xF>(m); m = dppaddf<0x140, 0xF>(m);
  m = dppaddf<0x142, 0xA>(m); m = dppaddf<0x143, 0xC>(m);
  return __int_as_float(__builtin_amdgcn_readlane(__float_as_int(m), 63));
}

// blocks [0, 1024): 128 thr = wave0 viterbi chain (batch=blk) + wave1 gather
// blocks [1024, 1056): each wave = MFMA forward scan for 16 batches
//   (tile = (blk-B_DIM)*2 + wave).
// fv recurrence in transposed p-space: PT_next = exp(trans) x PT via
// v_mfma_f32_16x16x16_f16.  K=16 shape: B-fragment layout (k=4*(l>>4)+e,
// n=l&15) == C/D layout (row=4*(l>>4)+r, col=l&15), so each step's output
// feeds the next step's B operand with zero cross-lane movement.
__global__ __launch_bounds__(128, 2)
void crf_fused(const float* __restrict__ em, const int* __restrict__ tags,
               const float* __restrict__ mask, const float* __restrict__ trans,
               const float* __restrict__ startT, const float* __restrict__ stopT,
               float* __restrict__ out)
{
  const int blk  = blockIdx.x;
  const int wave = threadIdx.x >> 6;
  const int l    = threadIdx.x & 63;

  if (blk >= B_DIM) {
    // ================= MFMA forward scan, 16 batches per wave ==============
    const int tile = (blk - B_DIM) * 2 + wave;   // 0..63
    const int a  = l >> 4;            // lane group 0..3
    const int n  = l & 15;            // batch-within-tile / A-row index
    const int bb = tile * 16 + n;
    const int bpi = (l ^ 32) << 2;    // ds_bpermute byte addr (lane^32)

    // A fragments: A[m][k] = exp(trans[16mt + n][16kf + 4a + e])
#define DECL_A(mt,kf) r4 A##mt##kf; {                                  \
      const float* tb = trans + (16*(mt) + n) * T_DIM + 16*(kf) + 4*a; \
      A##mt##kf[0] = (_Float16)EXP2F(tb[0] * L2E);                     \
      A##mt##kf[1] = (_Float16)EXP2F(tb[1] * L2E);                     \
      A##mt##kf[2] = (_Float16)EXP2F(tb[2] * L2E);                     \
      A##mt##kf[3] = (_Float16)EXP2F(tb[3] * L2E); }
    DECL_A(0,0) DECL_A(0,1) DECL_A(0,2)
    DECL_A(1,0) DECL_A(1,1) DECL_A(1,2)
    DECL_A(2,0) DECL_A(2,1) DECL_A(2,2)
    asm volatile("" : "+v"(A00), "+v"(A01), "+v"(A02),
                      "+v"(A10), "+v"(A11), "+v"(A12),
                      "+v"(A20), "+v"(A21), "+v"(A22));

    // state P{mt}[r] = p of tag 16mt+4a+r, batch bb (true p = P * 2^k2)
    const float* e0 = em + (size_t)bb * T_DIM;
    f4 P0, P1, P2;
#pragma unroll
    for (int r = 0; r < 4; ++r) {
      P0[r] = EXP2F((startT[ 0 + 4*a + r] + e0[ 0 + 4*a + r]) * L2E);
      P1[r] = EXP2F((startT[16 + 4*a + r] + e0[16 + 4*a + r]) * L2E);
      P2[r] = EXP2F((startT[32 + 4*a + r] + e0[32 + 4*a + r]) * L2E);
    }
    float k2 = 0.f;

    // 3-deep prefetch: EA=row s, EB=s+1, EC=s+2; load row s+3 each step
    const size_t rstep = (size_t)B_DIM * T_DIM;
    const float* pe = em + rstep + (size_t)bb * T_DIM + 4*a;   // row 1
    f4 EA0 = *(const f4*)(pe +  0), EA1 = *(const f4*)(pe + 16),
       EA2 = *(const f4*)(pe + 32);
    pe += rstep;
    f4 EB0 = *(const f4*)(pe +  0), EB1 = *(const f4*)(pe + 16),
       EB2 = *(const f4*)(pe + 32);
    pe += rstep;
    f4 EC0 = *(const f4*)(pe +  0), EC1 = *(const f4*)(pe + 16),
       EC2 = *(const f4*)(pe + 32);
    pe += rstep;                                               // -> row 4
    float mkA = mask[1*B_DIM + bb], mkB = mask[2*B_DIM + bb],
          mkC = mask[3*B_DIM + bb];
    const float* pm = mask + 4*B_DIM + bb;

#define FMSTEP(LOAD)                                                      \
    { f4 D0, D1, D2; float mkD;                                           \
      if (LOAD) { D0 = *(const f4*)(pe); D1 = *(const f4*)(pe + 16);      \
                  D2 = *(const f4*)(pe + 32); pe += rstep;                \
                  mkD = *pm; pm += B_DIM; }                               \
      else      { D0 = EC0; D1 = EC1; D2 = EC2; mkD = mkC; }              \
      /* per-batch exact max -> power-of-2 rescale */                     \
      float mx = fmaxf(fmaxf(fmaxf(P0[0],P0[1]), fmaxf(P0[2],P0[3])),     \
                 fmaxf(fmaxf(fmaxf(P1[0],P1[1]), fmaxf(P1[2],P1[3])),     \
                       fmaxf(fmaxf(P2[0],P2[1]), fmaxf(P2[2],P2[3]))));   \
      mx = fmaxf(mx, __int_as_float(__builtin_amdgcn_ds_swizzle(          \
                       __float_as_int(mx), 0x401F)));                     \
      mx = fmaxf(mx, __int_as_float(__builtin_amdgcn_ds_bpermute(         \
                       bpi, __float_as_int(mx))));                        \
      int ee  = (__float_as_int(mx) >> 23) - 126;                         \
      float c = __int_as_float((135 - ee) << 23);      /* 2^(8-ee) */     \
      k2 += (float)(ee - 8);                                              \
      r4 B0, B1, B2;                                                      \
      B0[0]=(_Float16)(P0[0]*c); B0[1]=(_Float16)(P0[1]*c);               \
      B0[2]=(_Float16)(P0[2]*c); B0[3]=(_Float16)(P0[3]*c);               \
      B1[0]=(_Float16)(P1[0]*c); B1[1]=(_Float16)(P1[1]*c);               \
      B1[2]=(_Float16)(P1[2]*c); B1[3]=(_Float16)(P1[3]*c);               \
      B2[0]=(_Float16)(P2[0]*c); B2[1]=(_Float16)(P2[1]*c);               \
      B2[2]=(_Float16)(P2[2]*c); B2[3]=(_Float16)(P2[3]*c);               \
      f4 Z = {0.f, 0.f, 0.f, 0.f};                                        \
      f4 C0 = MFMA16(A00, B0, Z); C0 = MFMA16(A01, B1, C0);               \
      C0 = MFMA16(A02, B2, C0);                                           \
      f4 C1 = MFMA16(A10, B0, Z); C1 = MFMA16(A11, B1, C1);               \
      C1 = MFMA16(A12, B2, C1);                                           \
      f4 C2 = MFMA16(A20, B0, Z); C2 = MFMA16(A21, B1, C2);               \
      C2 = MFMA16(A22, B2, C2);                                           \
      _Pragma("unroll")                                                   \
      for (int r = 0; r < 4; ++r) {                                       \
        float ps0 = P0[r]*c, q0 = C0[r]*EXP2F(EA0[r]*L2E);                \
        P0[r] = fmaf(mkA, q0 - ps0, ps0);                                 \
        float ps1 = P1[r]*c, q1 = C1[r]*EXP2F(EA1[r]*L2E);                \
        P1[r] = fmaf(mkA, q1 - ps1, ps1);                                 \
        float ps2 = P2[r]*c, q2 = C2[r]*EXP2F(EA2[r]*L2E);                \
        P2[r] = fmaf(mkA, q2 - ps2, ps2);                                 \
      }                                                                   \
      EA0 = EB0; EA1 = EB1; EA2 = EB2;                                    \
      EB0 = EC0; EB1 = EC1; EB2 = EC2;                                    \
      EC0 = D0;  EC1 = D1;  EC2 = D2;                                     \
      mkA = mkB; mkB = mkC; mkC = mkD; }

#pragma unroll 2
    for (int s = 1; s <= 508; ++s) FMSTEP(true)
    FMSTEP(false) FMSTEP(false) FMSTEP(false)          // s = 509..511

    float part = 0.f;
#pragma unroll
    for (int r = 0; r < 4; ++r) {
      part = fmaf(P0[r], EXP2F(stopT[ 0 + 4*a + r] * L2E), part);
      part = fmaf(P1[r], EXP2F(stopT[16 + 4*a + r] * L2E), part);
      part = fmaf(P2[r], EXP2F(stopT[32 + 4*a + r] * L2E), part);
    }
    part += __int_as_float(__builtin_amdgcn_ds_swizzle(
                __float_as_int(part), 0x401F));
    part += __int_as_float(__builtin_amdgcn_ds_bpermute(
                bpi, __float_as_int(part)));
    float alpha = LN2 * (k2 + LOG2F(part));
    if (a == 0) out[1 + B_DIM + bb] = alpha;
    return;
  }

  if (wave == 1) {                       // ---- real-path gather ----
    const int b = blk;
    float acc = 0.f;
#pragma unroll
    for (int k = 0; k < 8; ++k) {
      int s = 1 + l + (k << 6);
      if (s < S_LEN) {
        int   tp  = tags[(s - 1) * B_DIM + b];
        int   tc  = tags[s * B_DIM + b];
        float mkv = mask[s * B_DIM + b];
        float emt = em[((size_t)s * B_DIM + b) * T_DIM + tc];
        acc = fmaf(mkv, trans[tp * T_DIM + tc] + emt, acc);
      }
    }
    float tot = wave_sum63(acc);
    if (l == 0)
      out[1 + b] = startT[tags[b]] +
                   stopT[tags[(S_LEN - 1) * B_DIM + b]] + tot;
    return;
  }

  // ================= viterbi chain (r16 structure, unchanged) =============
  const int b  = blk;
  const int ri = (l < T_DIM) ? l : (T_DIM - 1);
  const float* emb = em + (size_t)b * T_DIM + ri;
  const size_t estep = (size_t)B_DIM * T_DIM;
  float e1 = emb[1*estep], e2 = emb[2*estep], e3 = emb[3*estep];
  float e4 = emb[4*estep], e5 = emb[5*estep], e6 = emb[6*estep];
  float mk1 = mask[1*B_DIM + b], mk2 = mask[2*B_DIM + b];
  float mk3 = mask[3*B_DIM + b], mk4 = mask[4*B_DIM + b];
  float mk5 = mask[5*B_DIM + b], mk6 = mask[6*B_DIM + b];
  const float* pf  = emb + 7*estep;
  const float* pmk = mask + 7*B_DIM + b;

#define SHIFT_REGS                                                   \
      e1 = e2; e2 = e3; e3 = e4; e4 = e5; e5 = e6; e6 = ep;          \
      mk1 = mk2; mk2 = mk3; mk3 = mk4; mk4 = mk5; mk5 = mk6; mk6 = mkp;

#define DECL_T(nn) __half2 T##nn = __floats2half2_rn( \
      trans[ri * T_DIM + 2*(nn)], trans[ri * T_DIM + 2*(nn) + 1]);
  DECL_T(0)  DECL_T(1)  DECL_T(2)  DECL_T(3)  DECL_T(4)  DECL_T(5)
  DECL_T(6)  DECL_T(7)  DECL_T(8)  DECL_T(9)  DECL_T(10) DECL_T(11)
  DECL_T(12) DECL_T(13) DECL_T(14) DECL_T(15) DECL_T(16) DECL_T(17)
  DECL_T(18) DECL_T(19) DECL_T(20) DECL_T(21) DECL_T(22) DECL_T(23)

  asm volatile("" : "+v"(T0), "+v"(T1), "+v"(T2), "+v"(T3),
    "+v"(T4), "+v"(T5), "+v"(T6), "+v"(T7), "+v"(T8), "+v"(T9),
    "+v"(T10), "+v"(T11), "+v"(T12), "+v"(T13), "+v"(T14),
    "+v"(T15), "+v"(T16), "+v"(T17), "+v"(T18), "+v"(T19),
    "+v"(T20), "+v"(T21), "+v"(T22), "+v"(T23));

  float v = startT[ri] + emb[0];
  const __half2 NEGI = __floats2half2_rn(-60000.f, -60000.f);
  float m_ref = wave_max63(v);

#define VVG(g, Ta, Tb, Tc, Td, Te, Tf)                 \
    { __half2 t0 = bpick(vp, 12*(g) + 0);              \
      __half2 t1 = bpick(vp, 12*(g) + 2);              \
      __half2 t2 = bpick(vp, 12*(g) + 4);              \
      __half2 t3 = bpick(vp, 12*(g) + 6);              \
      __half2 t4 = bpick(vp, 12*(g) + 8);              \
      __half2 t5 = bpick(vp, 12*(g) + 10);             \
      m0 = hmax2(m0, __hadd2(t0, Ta));                 \
      m1 = hmax2(m1, __hadd2(t1, Tb));                 \
      m2 = hmax2(m2, __hadd2(t2, Tc));                 \
      m3 = hmax2(m3, __hadd2(t3, Td));                 \
      m0 = hmax2(m0, __hadd2(t4, Te));                 \
      m1 = hmax2(m1, __hadd2(t5, Tf)); }

#define VV_STEP(LOAD, DOTREE)                                        \
    { float ep, mkp;                                                 \
      if (LOAD) { ep = *pf; pf += estep; mkp = *pmk; pmk += B_DIM; } \
      else      { ep = e6; mkp = mk6; }                              \
      if (DOTREE) m_ref = wave_max63(v);                             \
      float vr  = v - m_ref;                                         \
      float vn_ = dppmovf<0xB1, 0xF>(vr);                            \
      __half2 vp = __floats2half2_rn(vr, vn_);                       \
      __half2 m0 = NEGI, m1 = NEGI, m2 = NEGI, m3 = NEGI;            \
      VVG(0, T0,  T1,  T2,  T3,  T4,  T5)                            \
      VVG(1, T6,  T7,  T8,  T9,  T10, T11)                           \
      VVG(2, T12, T13, T14, T15, T16, T17)                           \
      VVG(3, T18, T19, T20, T21, T22, T23)                           \
      m0 = hmax2(hmax2(m0, m1), hmax2(m2, m3));                      \
      float mx = fmaxf(__low2float(m0), __high2float(m0));           \
      float vnew = e1 + m_ref + mx;                                  \
      v = fmaf(mk1, vnew - v, v);                                    \
      SHIFT_REGS }

#pragma unroll 8
  for (int s = 1; s <= 504; ++s) VV_STEP(true, ((s & 7) == 0))
  VV_STEP(true, false)
  VV_STEP(false, false) VV_STEP(false, false) VV_STEP(false, false)
  VV_STEP(false, false) VV_STEP(false, false) VV_STEP(false, false)

  float best = wave_max63(v + stopT[ri]);
  if (l == 0) out[1 + 2 * B_DIM + b] = best;
}

// ---- loss = mean(alpha - real) ----
__global__ __launch_bounds__(256)
void crf_loss(float* __restrict__ out)
{
  __shared__ float red[256];
  int t = threadIdx.x;
  float a = 0.f;
  for (int b = t; b < B_DIM; b += 256)
    a += out[1 + B_DIM + b] - out[1 + b];
  red[t] = a;
  __syncthreads();
  for (int w = 128; w > 0; w >>= 1) {
    if (t < w) red[t] += red[t + w];
    __syncthreads();
  }
  if (t == 0) out[0] = red[0] * (1.0f / B_DIM);
}

extern "C" void kernel_launch(void* const* d_in, const int* in_sizes, int n_in,
                              void* d_out, int out_size, void* d_ws, size_t ws_size,
                              hipStream_t stream) {
  (void)in_sizes; (void)n_in; (void)d_ws; (void)ws_size; (void)out_size;
  const float* em     = (const float*)d_in[0];
  const int*   tags   = (const int*)d_in[1];
  const float* mask   = (const float*)d_in[2];
  const float* trans  = (const float*)d_in[3];
  const float* startT = (const float*)d_in[4];
  const float* stopT  = (const float*)d_in[5];
  float* out = (float*)d_out;

  hipLaunchKernelGGL(crf_fused, dim3(B_DIM + 32), dim3(128), 0, stream,
                     em, tags, mask, trans, startT, stopT, out);
  hipLaunchKernelGGL(crf_loss, dim3(1), dim3(256), 0, stream, out);
}

// Round 22
// 245.210 us; speedup vs baseline: 1.0528x; 1.0528x over previous
//
#include <hip/hip_runtime.h>
#include <hip/hip_fp16.h>

#define S_LEN 512
#define B_DIM 1024
#define T_DIM 48
#define L2E 1.4426950408889634f
#define LN2 0.6931471805599453f

#define EXP2F(x) __builtin_amdgcn_exp2f(x)
#define LOG2F(x) __builtin_amdgcn_logf(x)

typedef _Float16 h2v __attribute__((ext_vector_type(2)));
typedef _Float16 r4  __attribute__((ext_vector_type(4)));
typedef float    f4  __attribute__((ext_vector_type(4)));

// v_mfma_f32_16x16x16_f16 ; guarded so the HOST pass never sees the builtin.
__device__ __forceinline__ f4 MFMA16(r4 a, r4 b, f4 c) {
#if defined(__HIP_DEVICE_COMPILE__)
  return __builtin_amdgcn_mfma_f32_16x16x16f16(a, b, c, 0, 0, 0);
#else
  (void)a; (void)b; return c;
#endif
}

// packed f16 max (ROCm 7.2 lacks __hmax2)
__device__ __forceinline__ __half2 hmax2(__half2 a, __half2 b) {
  h2v r = __builtin_elementwise_max(__builtin_bit_cast(h2v, a),
                                    __builtin_bit_cast(h2v, b));
  return __builtin_bit_cast(__half2, r);
}
__device__ __forceinline__ __half2 bpick(__half2 src, int lane) {
  int s = __builtin_amdgcn_readlane(__builtin_bit_cast(int, src), lane);
  return __builtin_bit_cast(__half2, s);
}

template <int CTRL, int RMASK>
__device__ __forceinline__ float dppmovf(float v) {
  return __int_as_float(__builtin_amdgcn_update_dpp(
      __float_as_int(v), __float_as_int(v), CTRL, RMASK, 0xF, false));
}
template <int CTRL, int RMASK>
__device__ __forceinline__ float dppmaxf(float m) {
  return fmaxf(m, dppmovf<CTRL, RMASK>(m));
}
template <int CTRL, int RMASK>
__device__ __forceinline__ float dppaddf(float m) {
  return m + dppmovf<CTRL, RMASK>(m);
}
__device__ __forceinline__ float wave_max63(float m) {
  m = dppmaxf<0xB1, 0xF>(m);  m = dppmaxf<0x4E, 0xF>(m);
  m = dppmaxf<0x141, 0xF>(m); m = dppmaxf<0x140, 0xF>(m);
  m = dppmaxf<0x142, 0xA>(m); m = dppmaxf<0x143, 0xC>(m);
  return __int_as_float(__builtin_amdgcn_readlane(__float_as_int(m), 63));
}
__device__ __forceinline__ float wave_sum63(float m) {
  m = dppaddf<0xB1, 0xF>(m);  m = dppaddf<0x4E, 0xF>(m);
  m = dppaddf<0x141, 0xF>(m); m = dppaddf<0x140, 0xF>(m);
  m = dppaddf<0x142, 0xA>(m); m = dppaddf<0x143, 0xC>(m);
  return __int_as_float(__builtin_amdgcn_readlane(__float_as_int(m), 63));
}

// blocks [0, 1024): 128 thr = wave0 viterbi chain (batch=blk) + wave1 gather
// blocks [1024, 1056): each wave = MFMA forward scan for 16 batches.
// fv: PT_next = exp(trans) x PT via v_mfma_f32_16x16x16_f16.
// Rescale: stale exponent at HALF GAIN.  With full gain the normalization
// feedback m_{s+1} = m_s - m_{s-1} + (g-6) has unit-circle roots e^{+-i.pi/3}
// (resonant, amplitude grows ~linearly -> f16 overflow -> NaN; r20/r21).
// Half gain: m_{s+1} = m_s - m_{s-1}/2 + (g-6), roots |x| = 0.707 -> damped.
// k2 bookkeeping is exact for ANY applied scale, so damping costs nothing.
__global__ __launch_bounds__(128, 2)
void crf_fused(const float* __restrict__ em, const int* __restrict__ tags,
               const float* __restrict__ mask, const float* __restrict__ trans,
               const float* __restrict__ startT, const float* __restrict__ stopT,
               float* __restrict__ out)
{
  const int blk  = blockIdx.x;
  const int wave = threadIdx.x >> 6;
  const int l    = threadIdx.x & 63;

  if (blk >= B_DIM) {
    // ================= MFMA forward scan, 16 batches per wave ==============
    const int tile = (blk - B_DIM) * 2 + wave;   // 0..63
    const int a  = l >> 4;            // lane group 0..3
    const int n  = l & 15;            // batch-within-tile / A-row index
    const int bb = tile * 16 + n;
    const int bpi = (l ^ 32) << 2;    // ds_bpermute byte addr (lane^32)

    // A fragments: A[m][k] = exp(trans[16mt + n][16kf + 4a + e])
#define DECL_A(mt,kf) r4 A##mt##kf; {                                  \
      const float* tb = trans + (16*(mt) + n) * T_DIM + 16*(kf) + 4*a; \
      A##mt##kf[0] = (_Float16)EXP2F(tb[0] * L2E);                     \
      A##mt##kf[1] = (_Float16)EXP2F(tb[1] * L2E);                     \
      A##mt##kf[2] = (_Float16)EXP2F(tb[2] * L2E);                     \
      A##mt##kf[3] = (_Float16)EXP2F(tb[3] * L2E); }
    DECL_A(0,0) DECL_A(0,1) DECL_A(0,2)
    DECL_A(1,0) DECL_A(1,1) DECL_A(1,2)
    DECL_A(2,0) DECL_A(2,1) DECL_A(2,2)
    asm volatile("" : "+v"(A00), "+v"(A01), "+v"(A02),
                      "+v"(A10), "+v"(A11), "+v"(A12),
                      "+v"(A20), "+v"(A21), "+v"(A22));

    // state P{mt}[r] = p of tag 16mt+4a+r, batch bb (true p = P * 2^k2)
    const float* e0 = em + (size_t)bb * T_DIM;
    f4 P0, P1, P2;
#pragma unroll
    for (int r = 0; r < 4; ++r) {
      P0[r] = EXP2F((startT[ 0 + 4*a + r] + e0[ 0 + 4*a + r]) * L2E);
      P1[r] = EXP2F((startT[16 + 4*a + r] + e0[16 + 4*a + r]) * L2E);
      P2[r] = EXP2F((startT[32 + 4*a + r] + e0[32 + 4*a + r]) * L2E);
    }
    float k2 = 0.f;

    // initial per-batch max exponent (exact), seeds the depth-2 stale queue
    float mx0 = fmaxf(fmaxf(fmaxf(P0[0],P0[1]), fmaxf(P0[2],P0[3])),
               fmaxf(fmaxf(fmaxf(P1[0],P1[1]), fmaxf(P1[2],P1[3])),
                     fmaxf(fmaxf(P2[0],P2[1]), fmaxf(P2[2],P2[3]))));
    mx0 = fmaxf(mx0, __int_as_float(__builtin_amdgcn_ds_swizzle(
                       __float_as_int(mx0), 0x401F)));
    mx0 = fmaxf(mx0, __int_as_float(__builtin_amdgcn_ds_bpermute(
                       bpi, __float_as_int(mx0))));
    int ee0 = (__float_as_int(mx0) >> 23) - 126;
    int eeA = ee0, eeB = ee0;        // depth-2: 1-step-stale consumption

    // 3-deep prefetch: EA=row s, EB=s+1, EC=s+2; load row s+3 each step
    const size_t rstep = (size_t)B_DIM * T_DIM;
    const float* pe = em + rstep + (size_t)bb * T_DIM + 4*a;   // row 1
    f4 EA0 = *(const f4*)(pe +  0), EA1 = *(const f4*)(pe + 16),
       EA2 = *(const f4*)(pe + 32);
    pe += rstep;
    f4 EB0 = *(const f4*)(pe +  0), EB1 = *(const f4*)(pe + 16),
       EB2 = *(const f4*)(pe + 32);
    pe += rstep;
    f4 EC0 = *(const f4*)(pe +  0), EC1 = *(const f4*)(pe + 16),
       EC2 = *(const f4*)(pe + 32);
    pe += rstep;                                               // -> row 4
    float mkA = mask[1*B_DIM + bb], mkB = mask[2*B_DIM + bb],
          mkC = mask[3*B_DIM + bb];
    const float* pm = mask + 4*B_DIM + bb;

#define FMSTEP(LOAD)                                                      \
    { f4 D0, D1, D2; float mkD;                                           \
      if (LOAD) { D0 = *(const f4*)(pe); D1 = *(const f4*)(pe + 16);      \
                  D2 = *(const f4*)(pe + 32); pe += rstep;                \
                  mkD = *pm; pm += B_DIM; }                               \
      else      { D0 = EC0; D1 = EC1; D2 = EC2; mkD = mkC; }              \
      int eh = eeA >> 1;                     /* HALF-GAIN stale scale */  \
      eh = eh > 60 ? 60 : (eh < -60 ? -60 : eh);                          \
      eeA = eeB;                                                          \
      float c = __int_as_float((121 - eh) << 23);    /* 2^(-6-eh) */      \
      k2 += (float)(eh + 6);                                              \
      r4 B0, B1, B2;                                                      \
      B0[0]=(_Float16)(P0[0]*c); B0[1]=(_Float16)(P0[1]*c);               \
      B0[2]=(_Float16)(P0[2]*c); B0[3]=(_Float16)(P0[3]*c);               \
      B1[0]=(_Float16)(P1[0]*c); B1[1]=(_Float16)(P1[1]*c);               \
      B1[2]=(_Float16)(P1[2]*c); B1[3]=(_Float16)(P1[3]*c);               \
      B2[0]=(_Float16)(P2[0]*c); B2[1]=(_Float16)(P2[1]*c);               \
      B2[2]=(_Float16)(P2[2]*c); B2[3]=(_Float16)(P2[3]*c);               \
      f4 Z = {0.f, 0.f, 0.f, 0.f};                                        \
      f4 C0 = MFMA16(A00, B0, Z); C0 = MFMA16(A01, B1, C0);               \
      C0 = MFMA16(A02, B2, C0);                                           \
      f4 C1 = MFMA16(A10, B0, Z); C1 = MFMA16(A11, B1, C1);               \
      C1 = MFMA16(A12, B2, C1);                                           \
      f4 C2 = MFMA16(A20, B0, Z); C2 = MFMA16(A21, B1, C2);               \
      C2 = MFMA16(A22, B2, C2);                                           \
      _Pragma("unroll")                                                   \
      for (int r = 0; r < 4; ++r) {                                       \
        float ps0 = P0[r]*c, q0 = C0[r]*EXP2F(EA0[r]*L2E);                \
        P0[r] = fmaf(mkA, q0 - ps0, ps0);                                 \
        float ps1 = P1[r]*c, q1 = C1[r]*EXP2F(EA1[r]*L2E);                \
        P1[r] = fmaf(mkA, q1 - ps1, ps1);                                 \
        float ps2 = P2[r]*c, q2 = C2[r]*EXP2F(EA2[r]*L2E);                \
        P2[r] = fmaf(mkA, q2 - ps2, ps2);                                 \
      }                                                                   \
      /* async max tree for ee, consumed at step s+2 (one step of slack) */ \
      float mx = fmaxf(fmaxf(fmaxf(P0[0],P0[1]), fmaxf(P0[2],P0[3])),     \
                 fmaxf(fmaxf(fmaxf(P1[0],P1[1]), fmaxf(P1[2],P1[3])),     \
                       fmaxf(fmaxf(P2[0],P2[1]), fmaxf(P2[2],P2[3]))));   \
      mx = fmaxf(mx, __int_as_float(__builtin_amdgcn_ds_swizzle(          \
                       __float_as_int(mx), 0x401F)));                     \
      mx = fmaxf(mx, __int_as_float(__builtin_amdgcn_ds_bpermute(         \
                       bpi, __float_as_int(mx))));                        \
      eeB = (__float_as_int(mx) >> 23) - 126;                             \
      EA0 = EB0; EA1 = EB1; EA2 = EB2;                                    \
      EB0 = EC0; EB1 = EC1; EB2 = EC2;                                    \
      EC0 = D0;  EC1 = D1;  EC2 = D2;                                     \
      mkA = mkB; mkB = mkC; mkC = mkD; }

#pragma unroll 2
    for (int s = 1; s <= 508; ++s) FMSTEP(true)
    FMSTEP(false) FMSTEP(false) FMSTEP(false)          // s = 509..511

    float part = 0.f;
#pragma unroll
    for (int r = 0; r < 4; ++r) {
      part = fmaf(P0[r], EXP2F(stopT[ 0 + 4*a + r] * L2E), part);
      part = fmaf(P1[r], EXP2F(stopT[16 + 4*a + r] * L2E), part);
      part = fmaf(P2[r], EXP2F(stopT[32 + 4*a + r] * L2E), part);
    }
    part += __int_as_float(__builtin_amdgcn_ds_swizzle(
                __float_as_int(part), 0x401F));
    part += __int_as_float(__builtin_amdgcn_ds_bpermute(
                bpi, __float_as_int(part)));
    float alpha = LN2 * (k2 + LOG2F(part));
    if (a == 0) out[1 + B_DIM + bb] = alpha;
    return;
  }

  if (wave == 1) {                       // ---- real-path gather ----
    const int b = blk;
    float acc = 0.f;
#pragma unroll
    for (int k = 0; k < 8; ++k) {
      int s = 1 + l + (k << 6);
      if (s < S_LEN) {
        int   tp  = tags[(s - 1) * B_DIM + b];
        int   tc  = tags[s * B_DIM + b];
        float mkv = mask[s * B_DIM + b];
        float emt = em[((size_t)s * B_DIM + b) * T_DIM + tc];
        acc = fmaf(mkv, trans[tp * T_DIM + tc] + emt, acc);
      }
    }
    float tot = wave_sum63(acc);
    if (l == 0)
      out[1 + b] = startT[tags[b]] +
                   stopT[tags[(S_LEN - 1) * B_DIM + b]] + tot;
    return;
  }

  // ================= viterbi chain (r16 structure, unchanged) =============
  const int b  = blk;
  const int ri = (l < T_DIM) ? l : (T_DIM - 1);
  const float* emb = em + (size_t)b * T_DIM + ri;
  const size_t estep = (size_t)B_DIM * T_DIM;
  float e1 = emb[1*estep], e2 = emb[2*estep], e3 = emb[3*estep];
  float e4 = emb[4*estep], e5 = emb[5*estep], e6 = emb[6*estep];
  float mk1 = mask[1*B_DIM + b], mk2 = mask[2*B_DIM + b];
  float mk3 = mask[3*B_DIM + b], mk4 = mask[4*B_DIM + b];
  float mk5 = mask[5*B_DIM + b], mk6 = mask[6*B_DIM + b];
  const float* pf  = emb + 7*estep;
  const float* pmk = mask + 7*B_DIM + b;

#define SHIFT_REGS                                                   \
      e1 = e2; e2 = e3; e3 = e4; e4 = e5; e5 = e6; e6 = ep;          \
      mk1 = mk2; mk2 = mk3; mk3 = mk4; mk4 = mk5; mk5 = mk6; mk6 = mkp;

#define DECL_T(nn) __half2 T##nn = __floats2half2_rn( \
      trans[ri * T_DIM + 2*(nn)], trans[ri * T_DIM + 2*(nn) + 1]);
  DECL_T(0)  DECL_T(1)  DECL_T(2)  DECL_T(3)  DECL_T(4)  DECL_T(5)
  DECL_T(6)  DECL_T(7)  DECL_T(8)  DECL_T(9)  DECL_T(10) DECL_T(11)
  DECL_T(12) DECL_T(13) DECL_T(14) DECL_T(15) DECL_T(16) DECL_T(17)
  DECL_T(18) DECL_T(19) DECL_T(20) DECL_T(21) DECL_T(22) DECL_T(23)

  asm volatile("" : "+v"(T0), "+v"(T1), "+v"(T2), "+v"(T3),
    "+v"(T4), "+v"(T5), "+v"(T6), "+v"(T7), "+v"(T8), "+v"(T9),
    "+v"(T10), "+v"(T11), "+v"(T12), "+v"(T13), "+v"(T14),
    "+v"(T15), "+v"(T16), "+v"(T17), "+v"(T18), "+v"(T19),
    "+v"(T20), "+v"(T21), "+v"(T22), "+v"(T23));

  float v = startT[ri] + emb[0];
  const __half2 NEGI = __floats2half2_rn(-60000.f, -60000.f);
  float m_ref = wave_max63(v);

#define VVG(g, Ta, Tb, Tc, Td, Te, Tf)                 \
    { __half2 t0 = bpick(vp, 12*(g) + 0);              \
      __half2 t1 = bpick(vp, 12*(g) + 2);              \
      __half2 t2 = bpick(vp, 12*(g) + 4);              \
      __half2 t3 = bpick(vp, 12*(g) + 6);              \
      __half2 t4 = bpick(vp, 12*(g) + 8);              \
      __half2 t5 = bpick(vp, 12*(g) + 10);             \
      m0 = hmax2(m0, __hadd2(t0, Ta));                 \
      m1 = hmax2(m1, __hadd2(t1, Tb));                 \
      m2 = hmax2(m2, __hadd2(t2, Tc));                 \
      m3 = hmax2(m3, __hadd2(t3, Td));                 \
      m0 = hmax2(m0, __hadd2(t4, Te));                 \
      m1 = hmax2(m1, __hadd2(t5, Tf)); }

#define VV_STEP(LOAD, DOTREE)                                        \
    { float ep, mkp;                                                 \
      if (LOAD) { ep = *pf; pf += estep; mkp = *pmk; pmk += B_DIM; } \
      else      { ep = e6; mkp = mk6; }                              \
      if (DOTREE) m_ref = wave_max63(v);                             \
      float vr  = v - m_ref;                                         \
      float vn_ = dppmovf<0xB1, 0xF>(vr);                            \
      __half2 vp = __floats2half2_rn(vr, vn_);                       \
      __half2 m0 = NEGI, m1 = NEGI, m2 = NEGI, m3 = NEGI;            \
      VVG(0, T0,  T1,  T2,  T3,  T4,  T5)                            \
      VVG(1, T6,  T7,  T8,  T9,  T10, T11)                           \
      VVG(2, T12, T13, T14, T15, T16, T17)                           \
      VVG(3, T18, T19, T20, T21, T22, T23)                           \
      m0 = hmax2(hmax2(m0, m1), hmax2(m2, m3));                      \
      float mx = fmaxf(__low2float(m0), __high2float(m0));           \
      float vnew = e1 + m_ref + mx;                                  \
      v = fmaf(mk1, vnew - v, v);                                    \
      SHIFT_REGS }

#pragma unroll 8
  for (int s = 1; s <= 504; ++s) VV_STEP(true, ((s & 7) == 0))
  VV_STEP(true, false)
  VV_STEP(false, false) VV_STEP(false, false) VV_STEP(false, false)
  VV_STEP(false, false) VV_STEP(false, false) VV_STEP(false, false)

  float best = wave_max63(v + stopT[ri]);
  if (l == 0) out[1 + 2 * B_DIM + b] = best;
}

// ---- loss = mean(alpha - real) ----
__global__ __launch_bounds__(256)
void crf_loss(float* __restrict__ out)
{
  __shared__ float red[256];
  int t = threadIdx.x;
  float a = 0.f;
  for (int b = t; b < B_DIM; b += 256)
    a += out[1 + B_DIM + b] - out[1 + b];
  red[t] = a;
  __syncthreads();
  for (int w = 128; w > 0; w >>= 1) {
    if (t < w) red[t] += red[t + w];
    __syncthreads();
  }
  if (t == 0) out[0] = red[0] * (1.0f / B_DIM);
}

extern "C" void kernel_launch(void* const* d_in, const int* in_sizes, int n_in,
                              void* d_out, int out_size, void* d_ws, size_t ws_size,
                              hipStream_t stream) {
  (void)in_sizes; (void)n_in; (void)d_ws; (void)ws_size; (void)out_size;
  const float* em     = (const float*)d_in[0];
  const int*   tags   = (const int*)d_in[1];
  const float* mask   = (const float*)d_in[2];
  const float* trans  = (const float*)d_in[3];
  const float* startT = (const float*)d_in[4];
  const float* stopT  = (const float*)d_in[5];
  float* out = (float*)d_out;

  hipLaunchKernelGGL(crf_fused, dim3(B_DIM + 32), dim3(128), 0, stream,
                     em, tags, mask, trans, startT, stopT, out);
  hipLaunchKernelGGL(crf_loss, dim3(1), dim3(256), 0, stream, out);
}

// Round 23
// 230.511 us; speedup vs baseline: 1.1200x; 1.0638x over previous
//
#include <hip/hip_runtime.h>
#include <hip/hip_fp16.h>

#define S_LEN 512
#define B_DIM 1024
#define T_DIM 48
#define L2E 1.4426950408889634f
#define LN2 0.6931471805599453f

#define EXP2F(x) __builtin_amdgcn_exp2f(x)
#define LOG2F(x) __builtin_amdgcn_logf(x)

typedef _Float16 h2v __attribute__((ext_vector_type(2)));
typedef _Float16 r4  __attribute__((ext_vector_type(4)));
typedef float    f4  __attribute__((ext_vector_type(4)));

// v_mfma_f32_16x16x16_f16 ; guarded so the HOST pass never sees the builtin.
__device__ __forceinline__ f4 MFMA16(r4 a, r4 b, f4 c) {
#if defined(__HIP_DEVICE_COMPILE__)
  return __builtin_amdgcn_mfma_f32_16x16x16f16(a, b, c, 0, 0, 0);
#else
  (void)a; (void)b; return c;
#endif
}

// packed f16 max (ROCm 7.2 lacks __hmax2)
__device__ __forceinline__ __half2 hmax2(__half2 a, __half2 b) {
  h2v r = __builtin_elementwise_max(__builtin_bit_cast(h2v, a),
                                    __builtin_bit_cast(h2v, b));
  return __builtin_bit_cast(__half2, r);
}
__device__ __forceinline__ __half2 bpick(__half2 src, int lane) {
  int s = __builtin_amdgcn_readlane(__builtin_bit_cast(int, src), lane);
  return __builtin_bit_cast(__half2, s);
}

template <int CTRL, int RMASK>
__device__ __forceinline__ float dppmovf(float v) {
  return __int_as_float(__builtin_amdgcn_update_dpp(
      __float_as_int(v), __float_as_int(v), CTRL, RMASK, 0xF, false));
}
template <int CTRL, int RMASK>
__device__ __forceinline__ float dppmaxf(float m) {
  return fmaxf(m, dppmovf<CTRL, RMASK>(m));
}
template <int CTRL, int RMASK>
__device__ __forceinline__ float dppaddf(float m) {
  return m + dppmovf<CTRL, RMASK>(m);
}
__device__ __forceinline__ float wave_max63(float m) {
  m = dppmaxf<0xB1, 0xF>(m);  m = dppmaxf<0x4E, 0xF>(m);
  m = dppmaxf<0x141, 0xF>(m); m = dppmaxf<0x140, 0xF>(m);
  m = dppmaxf<0x142, 0xA>(m); m = dppmaxf<0x143, 0xC>(m);
  return __int_as_float(__builtin_amdgcn_readlane(__float_as_int(m), 63));
}
__device__ __forceinline__ float wave_sum63(float m) {
  m = dppaddf<0xB1, 0xF>(m);  m = dppaddf<0x4E, 0xF>(m);
  m = dppaddf<0x141, 0xF>(m); m = dppaddf<0x140, 0xF>(m);
  m = dppaddf<0x142, 0xA>(m); m = dppaddf<0x143, 0xC>(m);
  return __int_as_float(__builtin_amdgcn_readlane(__float_as_int(m), 63));
}

// blocks [0, 32): each wave = MFMA forward scan for 16 batches (fv FIRST in
//   grid order -> co-resident with early vv blocks -> L2 sharing of em).
// blocks [32, 1056): 128 thr = wave0 viterbi chain (b=blk-32) + wave1 gather.
// fv: PT_next = exp(trans) x PT via v_mfma_f32_16x16x16_f16.
//  - half-gain damped stale-exponent rescale (r22, stable)
//  - exp-hoist: em row exp'd ONE STEP before use (off recurrence path)
//  - depth-4 raw prefetch: load row s+4 at step s (load->exp = 3 steps)
__global__ __launch_bounds__(128, 2)
void crf_fused(const float* __restrict__ em, const int* __restrict__ tags,
               const float* __restrict__ mask, const float* __restrict__ trans,
               const float* __restrict__ startT, const float* __restrict__ stopT,
               float* __restrict__ out)
{
  const int blk  = blockIdx.x;
  const int wave = threadIdx.x >> 6;
  const int l    = threadIdx.x & 63;

  if (blk < 32) {
    // ================= MFMA forward scan, 16 batches per wave ==============
    const int tile = blk * 2 + wave;  // 0..63
    const int a  = l >> 4;            // lane group 0..3
    const int n  = l & 15;            // batch-within-tile / A-row index
    const int bb = tile * 16 + n;
    const int bpi = (l ^ 32) << 2;    // ds_bpermute byte addr (lane^32)

    // A fragments: A[m][k] = exp(trans[16mt + n][16kf + 4a + e])
#define DECL_A(mt,kf) r4 A##mt##kf; {                                  \
      const float* tb = trans + (16*(mt) + n) * T_DIM + 16*(kf) + 4*a; \
      A##mt##kf[0] = (_Float16)EXP2F(tb[0] * L2E);                     \
      A##mt##kf[1] = (_Float16)EXP2F(tb[1] * L2E);                     \
      A##mt##kf[2] = (_Float16)EXP2F(tb[2] * L2E);                     \
      A##mt##kf[3] = (_Float16)EXP2F(tb[3] * L2E); }
    DECL_A(0,0) DECL_A(0,1) DECL_A(0,2)
    DECL_A(1,0) DECL_A(1,1) DECL_A(1,2)
    DECL_A(2,0) DECL_A(2,1) DECL_A(2,2)
    asm volatile("" : "+v"(A00), "+v"(A01), "+v"(A02),
                      "+v"(A10), "+v"(A11), "+v"(A12),
                      "+v"(A20), "+v"(A21), "+v"(A22));

    // state P{mt}[r] = p of tag 16mt+4a+r, batch bb (true p = P * 2^k2)
    const float* e0 = em + (size_t)bb * T_DIM;
    f4 P0, P1, P2;
#pragma unroll
    for (int r = 0; r < 4; ++r) {
      P0[r] = EXP2F((startT[ 0 + 4*a + r] + e0[ 0 + 4*a + r]) * L2E);
      P1[r] = EXP2F((startT[16 + 4*a + r] + e0[16 + 4*a + r]) * L2E);
      P2[r] = EXP2F((startT[32 + 4*a + r] + e0[32 + 4*a + r]) * L2E);
    }
    float k2 = 0.f;

    // initial per-batch max exponent (exact), seeds the depth-2 stale queue
    float mx0 = fmaxf(fmaxf(fmaxf(P0[0],P0[1]), fmaxf(P0[2],P0[3])),
               fmaxf(fmaxf(fmaxf(P1[0],P1[1]), fmaxf(P1[2],P1[3])),
                     fmaxf(fmaxf(P2[0],P2[1]), fmaxf(P2[2],P2[3]))));
    mx0 = fmaxf(mx0, __int_as_float(__builtin_amdgcn_ds_swizzle(
                       __float_as_int(mx0), 0x401F)));
    mx0 = fmaxf(mx0, __int_as_float(__builtin_amdgcn_ds_bpermute(
                       bpi, __float_as_int(mx0))));
    int ee0 = (__float_as_int(mx0) >> 23) - 126;
    int eeA = ee0, eeB = ee0;        // depth-2: 1-step-stale consumption

    // pipeline: XA = exp2(row s) ready; raw EB=s+1, EC=s+2, ED=s+3;
    // step s loads row s+4 (load->exp distance = 3 steps)
    const size_t rstep = (size_t)B_DIM * T_DIM;
    const float* pe = em + rstep + (size_t)bb * T_DIM + 4*a;   // row 1
    f4 XA0, XA1, XA2;
    {
      f4 t0 = *(const f4*)(pe), t1 = *(const f4*)(pe + 16),
         t2 = *(const f4*)(pe + 32);
#pragma unroll
      for (int r = 0; r < 4; ++r) {
        XA0[r] = EXP2F(t0[r] * L2E);
        XA1[r] = EXP2F(t1[r] * L2E);
        XA2[r] = EXP2F(t2[r] * L2E);
      }
    }
    pe += rstep;
    f4 EB0 = *(const f4*)(pe), EB1 = *(const f4*)(pe + 16),
       EB2 = *(const f4*)(pe + 32);
    pe += rstep;
    f4 EC0 = *(const f4*)(pe), EC1 = *(const f4*)(pe + 16),
       EC2 = *(const f4*)(pe + 32);
    pe += rstep;
    f4 ED0 = *(const f4*)(pe), ED1 = *(const f4*)(pe + 16),
       ED2 = *(const f4*)(pe + 32);
    pe += rstep;                                               // -> row 5
    float mkA = mask[1*B_DIM + bb], mkB = mask[2*B_DIM + bb],
          mkC = mask[3*B_DIM + bb], mkD = mask[4*B_DIM + bb];
    const float* pm = mask + 5*B_DIM + bb;

#define FMSTEP(LOAD)                                                      \
    { f4 D0, D1, D2; float mkN;                                           \
      if (LOAD) { D0 = *(const f4*)(pe); D1 = *(const f4*)(pe + 16);      \
                  D2 = *(const f4*)(pe + 32); pe += rstep;                \
                  mkN = *pm; pm += B_DIM; }                               \
      else      { D0 = ED0; D1 = ED1; D2 = ED2; mkN = mkD; }              \
      int eh = eeA >> 1;                     /* HALF-GAIN stale scale */  \
      eh = eh > 60 ? 60 : (eh < -60 ? -60 : eh);                          \
      eeA = eeB;                                                          \
      float c = __int_as_float((121 - eh) << 23);    /* 2^(-6-eh) */      \
      k2 += (float)(eh + 6);                                              \
      r4 B0, B1, B2;                                                      \
      B0[0]=(_Float16)(P0[0]*c); B0[1]=(_Float16)(P0[1]*c);               \
      B0[2]=(_Float16)(P0[2]*c); B0[3]=(_Float16)(P0[3]*c);               \
      B1[0]=(_Float16)(P1[0]*c); B1[1]=(_Float16)(P1[1]*c);               \
      B1[2]=(_Float16)(P1[2]*c); B1[3]=(_Float16)(P1[3]*c);               \
      B2[0]=(_Float16)(P2[0]*c); B2[1]=(_Float16)(P2[1]*c);               \
      B2[2]=(_Float16)(P2[2]*c); B2[3]=(_Float16)(P2[3]*c);               \
      f4 Z = {0.f, 0.f, 0.f, 0.f};                                        \
      f4 C0 = MFMA16(A00, B0, Z); C0 = MFMA16(A01, B1, C0);               \
      C0 = MFMA16(A02, B2, C0);                                           \
      f4 C1 = MFMA16(A10, B0, Z); C1 = MFMA16(A11, B1, C1);               \
      C1 = MFMA16(A12, B2, C1);                                           \
      f4 C2 = MFMA16(A20, B0, Z); C2 = MFMA16(A21, B1, C2);               \
      C2 = MFMA16(A22, B2, C2);                                           \
      /* exp-hoist: exponentiate NEXT step's em row (off recurrence) */   \
      f4 XN0, XN1, XN2;                                                   \
      _Pragma("unroll")                                                   \
      for (int r = 0; r < 4; ++r) {                                       \
        XN0[r] = EXP2F(EB0[r] * L2E);                                     \
        XN1[r] = EXP2F(EB1[r] * L2E);                                     \
        XN2[r] = EXP2F(EB2[r] * L2E);                                     \
      }                                                                   \
      _Pragma("unroll")                                                   \
      for (int r = 0; r < 4; ++r) {                                       \
        float ps0 = P0[r]*c, q0 = C0[r]*XA0[r];                           \
        P0[r] = fmaf(mkA, q0 - ps0, ps0);                                 \
        float ps1 = P1[r]*c, q1 = C1[r]*XA1[r];                           \
        P1[r] = fmaf(mkA, q1 - ps1, ps1);                                 \
        float ps2 = P2[r]*c, q2 = C2[r]*XA2[r];                           \
        P2[r] = fmaf(mkA, q2 - ps2, ps2);                                 \
      }                                                                   \
      /* async max tree for ee, consumed at step s+2 (one step of slack) */ \
      float mx = fmaxf(fmaxf(fmaxf(P0[0],P0[1]), fmaxf(P0[2],P0[3])),     \
                 fmaxf(fmaxf(fmaxf(P1[0],P1[1]), fmaxf(P1[2],P1[3])),     \
                       fmaxf(fmaxf(P2[0],P2[1]), fmaxf(P2[2],P2[3]))));   \
      mx = fmaxf(mx, __int_as_float(__builtin_amdgcn_ds_swizzle(          \
                       __float_as_int(mx), 0x401F)));                     \
      mx = fmaxf(mx, __int_as_float(__builtin_amdgcn_ds_bpermute(         \
                       bpi, __float_as_int(mx))));                        \
      eeB = (__float_as_int(mx) >> 23) - 126;                             \
      XA0 = XN0; XA1 = XN1; XA2 = XN2;                                    \
      EB0 = EC0; EB1 = EC1; EB2 = EC2;                                    \
      EC0 = ED0; EC1 = ED1; EC2 = ED2;                                    \
      ED0 = D0;  ED1 = D1;  ED2 = D2;                                     \
      mkA = mkB; mkB = mkC; mkC = mkD; mkD = mkN; }

#pragma unroll 2
    for (int s = 1; s <= 507; ++s) FMSTEP(true)
    FMSTEP(false) FMSTEP(false)                        // s = 508, 509
    FMSTEP(false) FMSTEP(false)                        // s = 510, 511

    float part = 0.f;
#pragma unroll
    for (int r = 0; r < 4; ++r) {
      part = fmaf(P0[r], EXP2F(stopT[ 0 + 4*a + r] * L2E), part);
      part = fmaf(P1[r], EXP2F(stopT[16 + 4*a + r] * L2E), part);
      part = fmaf(P2[r], EXP2F(stopT[32 + 4*a + r] * L2E), part);
    }
    part += __int_as_float(__builtin_amdgcn_ds_swizzle(
                __float_as_int(part), 0x401F));
    part += __int_as_float(__builtin_amdgcn_ds_bpermute(
                bpi, __float_as_int(part)));
    float alpha = LN2 * (k2 + LOG2F(part));
    if (a == 0) out[1 + B_DIM + bb] = alpha;
    return;
  }

  const int b = blk - 32;

  if (wave == 1) {                       // ---- real-path gather ----
    float acc = 0.f;
#pragma unroll
    for (int k = 0; k < 8; ++k) {
      int s = 1 + l + (k << 6);
      if (s < S_LEN) {
        int   tp  = tags[(s - 1) * B_DIM + b];
        int   tc  = tags[s * B_DIM + b];
        float mkv = mask[s * B_DIM + b];
        float emt = em[((size_t)s * B_DIM + b) * T_DIM + tc];
        acc = fmaf(mkv, trans[tp * T_DIM + tc] + emt, acc);
      }
    }
    float tot = wave_sum63(acc);
    if (l == 0)
      out[1 + b] = startT[tags[b]] +
                   stopT[tags[(S_LEN - 1) * B_DIM + b]] + tot;
    return;
  }

  // ================= viterbi chain (r16 structure, unchanged) =============
  const int ri = (l < T_DIM) ? l : (T_DIM - 1);
  const float* emb = em + (size_t)b * T_DIM + ri;
  const size_t estep = (size_t)B_DIM * T_DIM;
  float e1 = emb[1*estep], e2 = emb[2*estep], e3 = emb[3*estep];
  float e4 = emb[4*estep], e5 = emb[5*estep], e6 = emb[6*estep];
  float mk1 = mask[1*B_DIM + b], mk2 = mask[2*B_DIM + b];
  float mk3 = mask[3*B_DIM + b], mk4 = mask[4*B_DIM + b];
  float mk5 = mask[5*B_DIM + b], mk6 = mask[6*B_DIM + b];
  const float* pf  = emb + 7*estep;
  const float* pmk = mask + 7*B_DIM + b;

#define SHIFT_REGS                                                   \
      e1 = e2; e2 = e3; e3 = e4; e4 = e5; e5 = e6; e6 = ep;          \
      mk1 = mk2; mk2 = mk3; mk3 = mk4; mk4 = mk5; mk5 = mk6; mk6 = mkp;

#define DECL_T(nn) __half2 T##nn = __floats2half2_rn( \
      trans[ri * T_DIM + 2*(nn)], trans[ri * T_DIM + 2*(nn) + 1]);
  DECL_T(0)  DECL_T(1)  DECL_T(2)  DECL_T(3)  DECL_T(4)  DECL_T(5)
  DECL_T(6)  DECL_T(7)  DECL_T(8)  DECL_T(9)  DECL_T(10) DECL_T(11)
  DECL_T(12) DECL_T(13) DECL_T(14) DECL_T(15) DECL_T(16) DECL_T(17)
  DECL_T(18) DECL_T(19) DECL_T(20) DECL_T(21) DECL_T(22) DECL_T(23)

  asm volatile("" : "+v"(T0), "+v"(T1), "+v"(T2), "+v"(T3),
    "+v"(T4), "+v"(T5), "+v"(T6), "+v"(T7), "+v"(T8), "+v"(T9),
    "+v"(T10), "+v"(T11), "+v"(T12), "+v"(T13), "+v"(T14),
    "+v"(T15), "+v"(T16), "+v"(T17), "+v"(T18), "+v"(T19),
    "+v"(T20), "+v"(T21), "+v"(T22), "+v"(T23));

  float v = startT[ri] + emb[0];
  const __half2 NEGI = __floats2half2_rn(-60000.f, -60000.f);
  float m_ref = wave_max63(v);

#define VVG(g, Ta, Tb, Tc, Td, Te, Tf)                 \
    { __half2 t0 = bpick(vp, 12*(g) + 0);              \
      __half2 t1 = bpick(vp, 12*(g) + 2);              \
      __half2 t2 = bpick(vp, 12*(g) + 4);              \
      __half2 t3 = bpick(vp, 12*(g) + 6);              \
      __half2 t4 = bpick(vp, 12*(g) + 8);              \
      __half2 t5 = bpick(vp, 12*(g) + 10);             \
      m0 = hmax2(m0, __hadd2(t0, Ta));                 \
      m1 = hmax2(m1, __hadd2(t1, Tb));                 \
      m2 = hmax2(m2, __hadd2(t2, Tc));                 \
      m3 = hmax2(m3, __hadd2(t3, Td));                 \
      m0 = hmax2(m0, __hadd2(t4, Te));                 \
      m1 = hmax2(m1, __hadd2(t5, Tf)); }

#define VV_STEP(LOAD, DOTREE)                                        \
    { float ep, mkp;                                                 \
      if (LOAD) { ep = *pf; pf += estep; mkp = *pmk; pmk += B_DIM; } \
      else      { ep = e6; mkp = mk6; }                              \
      if (DOTREE) m_ref = wave_max63(v);                             \
      float vr  = v - m_ref;                                         \
      float vn_ = dppmovf<0xB1, 0xF>(vr);                            \
      __half2 vp = __floats2half2_rn(vr, vn_);                       \
      __half2 m0 = NEGI, m1 = NEGI, m2 = NEGI, m3 = NEGI;            \
      VVG(0, T0,  T1,  T2,  T3,  T4,  T5)                            \
      VVG(1, T6,  T7,  T8,  T9,  T10, T11)                           \
      VVG(2, T12, T13, T14, T15, T16, T17)                           \
      VVG(3, T18, T19, T20, T21, T22, T23)                           \
      m0 = hmax2(hmax2(m0, m1), hmax2(m2, m3));                      \
      float mx = fmaxf(__low2float(m0), __high2float(m0));           \
      float vnew = e1 + m_ref + mx;                                  \
      v = fmaf(mk1, vnew - v, v);                                    \
      SHIFT_REGS }

#pragma unroll 8
  for (int s = 1; s <= 504; ++s) VV_STEP(true, ((s & 7) == 0))
  VV_STEP(true, false)
  VV_STEP(false, false) VV_STEP(false, false) VV_STEP(false, false)
  VV_STEP(false, false) VV_STEP(false, false) VV_STEP(false, false)

  float best = wave_max63(v + stopT[ri]);
  if (l == 0) out[1 + 2 * B_DIM + b] = best;
}

// ---- loss = mean(alpha - real) ----
__global__ __launch_bounds__(256)
void crf_loss(float* __restrict__ out)
{
  __shared__ float red[256];
  int t = threadIdx.x;
  float a = 0.f;
  for (int b = t; b < B_DIM; b += 256)
    a += out[1 + B_DIM + b] - out[1 + b];
  red[t] = a;
  __syncthreads();
  for (int w = 128; w > 0; w >>= 1) {
    if (t < w) red[t] += red[t + w];
    __syncthreads();
  }
  if (t == 0) out[0] = red[0] * (1.0f / B_DIM);
}

extern "C" void kernel_launch(void* const* d_in, const int* in_sizes, int n_in,
                              void* d_out, int out_size, void* d_ws, size_t ws_size,
                              hipStream_t stream) {
  (void)in_sizes; (void)n_in; (void)d_ws; (void)ws_size; (void)out_size;
  const float* em     = (const float*)d_in[0];
  const int*   tags   = (const int*)d_in[1];
  const float* mask   = (const float*)d_in[2];
  const float* trans  = (const float*)d_in[3];
  const float* startT = (const float*)d_in[4];
  const float* stopT  = (const float*)d_in[5];
  float* out = (float*)d_out;

  hipLaunchKernelGGL(crf_fused, dim3(B_DIM + 32), dim3(128), 0, stream,
                     em, tags, mask, trans, startT, stopT, out);
  hipLaunchKernelGGL(crf_loss, dim3(1), dim3(256), 0, stream, out);
}

// Round 24
// 201.266 us; speedup vs baseline: 1.2827x; 1.1453x over previous
//
#include <hip/hip_runtime.h>
#include <hip/hip_fp16.h>

#define S_LEN 512
#define B_DIM 1024
#define T_DIM 48
#define L2E 1.4426950408889634f
#define LN2 0.6931471805599453f

// v_exp_f32 computes 2^x ; v_log_f32 computes log2(x)
#define EXP2F(x) __builtin_amdgcn_exp2f(x)
#define LOG2F(x) __builtin_amdgcn_logf(x)

typedef _Float16 h2v __attribute__((ext_vector_type(2)));

// packed f16 max (ROCm 7.2 lacks __hmax2)
__device__ __forceinline__ __half2 hmax2(__half2 a, __half2 b) {
  h2v r = __builtin_elementwise_max(__builtin_bit_cast(h2v, a),
                                    __builtin_bit_cast(h2v, b));
  return __builtin_bit_cast(__half2, r);
}

// broadcast the 32-bit pair held by `lane` to all lanes (readlane -> SGPR)
__device__ __forceinline__ __half2 bpick(__half2 src, int lane) {
  int s = __builtin_amdgcn_readlane(__builtin_bit_cast(int, src), lane);
  return __builtin_bit_cast(__half2, s);
}

// ---- DPP wave-64 reduction helpers (full result valid in lane 63) ----
template <int CTRL, int RMASK>
__device__ __forceinline__ float dppmovf(float v) {
  return __int_as_float(__builtin_amdgcn_update_dpp(
      __float_as_int(v), __float_as_int(v), CTRL, RMASK, 0xF, false));
}
template <int CTRL, int RMASK>
__device__ __forceinline__ float dppmaxf(float m) {
  return fmaxf(m, dppmovf<CTRL, RMASK>(m));
}
template <int CTRL, int RMASK>
__device__ __forceinline__ float dppaddf(float m) {
  return m + dppmovf<CTRL, RMASK>(m);
}

__device__ __forceinline__ float wave_max63(float m) {
  m = dppmaxf<0xB1, 0xF>(m);   // xor 1
  m = dppmaxf<0x4E, 0xF>(m);   // xor 2
  m = dppmaxf<0x141, 0xF>(m);  // xor 4 (row_half_mirror)
  m = dppmaxf<0x140, 0xF>(m);  // xor 8 (row_mirror)
  m = dppmaxf<0x142, 0xA>(m);  // row_bcast15 -> rows 1,3
  m = dppmaxf<0x143, 0xC>(m);  // row_bcast31 -> rows 2,3 ; lane63 = full max
  return __int_as_float(__builtin_amdgcn_readlane(__float_as_int(m), 63));
}
__device__ __forceinline__ float wave_sum63(float m) {
  m = dppaddf<0xB1, 0xF>(m);
  m = dppaddf<0x4E, 0xF>(m);
  m = dppaddf<0x141, 0xF>(m);
  m = dppaddf<0x140, 0xF>(m);
  m = dppaddf<0x142, 0xA>(m);
  m = dppaddf<0x143, 0xC>(m);
  return __int_as_float(__builtin_amdgcn_readlane(__float_as_int(m), 63));
}

// One block = 192 threads = 3 waves, ALL FOR THE SAME batch b:
//   wave 0: forward (LSE) chain, exp-domain state
//   wave 1: viterbi (max) chain, stale-max-8 rebase
//   wave 2: real-path gather (finishes in ~8us, then frees the SIMD slot;
//           its ahead-of-scan em reads prefetch rows into the CU's L1)
// This is the max-occupancy structure for 1024 sequential chains (3072
// waves = 3/SIMD): co-resident waves hide each other's readlane/DPP
// hazards. Empirically fastest (r16 = 201.5 us); MFMA-fv variants
// (r19-r23) all lost because 64 waves issue-serialize at 1 wave/SIMD.
__global__ __launch_bounds__(192, 3)
void crf_fused(const float* __restrict__ em, const int* __restrict__ tags,
               const float* __restrict__ mask, const float* __restrict__ trans,
               const float* __restrict__ startT, const float* __restrict__ stopT,
               float* __restrict__ out)
{
  const int b    = blockIdx.x;
  const int wave = threadIdx.x >> 6;
  const int i    = threadIdx.x & 63;

  if (wave == 2) {                         // ---- real-path score ----
    float acc = 0.f;
#pragma unroll
    for (int k = 0; k < 8; ++k) {
      int s = 1 + i + (k << 6);
      if (s < S_LEN) {
        int   tp  = tags[(s - 1) * B_DIM + b];
        int   tc  = tags[s * B_DIM + b];
        float mkv = mask[s * B_DIM + b];
        float emt = em[((size_t)s * B_DIM + b) * T_DIM + tc];
        acc = fmaf(mkv, trans[tp * T_DIM + tc] + emt, acc);
      }
    }
    float tot = wave_sum63(acc);
    if (i == 0)
      out[1 + b] = startT[tags[b]] + stopT[tags[(S_LEN - 1) * B_DIM + b]] + tot;
    return;
  }

  const int ri = (i < T_DIM) ? i : (T_DIM - 1);

  const float* emb = em + (size_t)b * T_DIM + ri;
  const size_t estep = (size_t)B_DIM * T_DIM;
  // 6-deep shift registers: e1..e6 = em rows s..s+5, mk1..mk6 = mask rows
  float e1 = emb[1 * estep], e2 = emb[2 * estep], e3 = emb[3 * estep];
  float e4 = emb[4 * estep], e5 = emb[5 * estep], e6 = emb[6 * estep];
  float mk1 = mask[1 * B_DIM + b], mk2 = mask[2 * B_DIM + b];
  float mk3 = mask[3 * B_DIM + b], mk4 = mask[4 * B_DIM + b];
  float mk5 = mask[5 * B_DIM + b], mk6 = mask[6 * B_DIM + b];
  const float* pf  = emb + 7 * estep;        // next em row to fetch (s+6)
  const float* pmk = mask + 7 * B_DIM + b;   // next mask row to fetch (s+6)

#define SHIFT_REGS                                                   \
      e1 = e2; e2 = e3; e3 = e4; e4 = e5; e5 = e6; e6 = ep;          \
      mk1 = mk2; mk2 = mk3; mk3 = mk4; mk4 = mk5; mk5 = mk6; mk6 = mkp;

  if (wave == 0) {
    // ---- forward chain, exp-domain state: fv = LN2*k2 + ln(p) ----
#define DECL_E(n) __half2 E##n = __floats2half2_rn( \
      EXP2F(trans[ri * T_DIM + 2*(n)    ] * L2E),   \
      EXP2F(trans[ri * T_DIM + 2*(n) + 1] * L2E));
    DECL_E(0)  DECL_E(1)  DECL_E(2)  DECL_E(3)  DECL_E(4)  DECL_E(5)
    DECL_E(6)  DECL_E(7)  DECL_E(8)  DECL_E(9)  DECL_E(10) DECL_E(11)
    DECL_E(12) DECL_E(13) DECL_E(14) DECL_E(15) DECL_E(16) DECL_E(17)
    DECL_E(18) DECL_E(19) DECL_E(20) DECL_E(21) DECL_E(22) DECL_E(23)

#define PIN_E asm("" : "+v"(E0), "+v"(E1), "+v"(E2), "+v"(E3),       \
      "+v"(E4), "+v"(E5), "+v"(E6), "+v"(E7), "+v"(E8), "+v"(E9),    \
      "+v"(E10), "+v"(E11), "+v"(E12), "+v"(E13), "+v"(E14),         \
      "+v"(E15), "+v"(E16), "+v"(E17), "+v"(E18), "+v"(E19),         \
      "+v"(E20), "+v"(E21), "+v"(E22), "+v"(E23));

    float p  = EXP2F((startT[ri] + emb[0]) * L2E);   // |fv0| <= ~9, f32 safe
    float k2 = 0.f;

#define FVG(g, Ea, Eb, Ec, Ed, Ee, Ef)                 \
    { __half2 t0 = bpick(pp, 12*(g) + 0);              \
      __half2 t1 = bpick(pp, 12*(g) + 2);              \
      __half2 t2 = bpick(pp, 12*(g) + 4);              \
      __half2 t3 = bpick(pp, 12*(g) + 6);              \
      __half2 t4 = bpick(pp, 12*(g) + 8);              \
      __half2 t5 = bpick(pp, 12*(g) + 10);             \
      a0 = __hfma2(t0, Ea, a0);                        \
      a1 = __hfma2(t1, Eb, a1);                        \
      a2 = __hfma2(t2, Ec, a2);                        \
      a3 = __hfma2(t3, Ed, a3);                        \
      a0 = __hfma2(t4, Ee, a0);                        \
      a1 = __hfma2(t5, Ef, a1); }

#define FV_STEP(LOAD)                                                \
    { float ep, mkp;                                                 \
      if (LOAD) { ep = *pf; pf += estep; mkp = *pmk; pmk += B_DIM; } \
      else      { ep = e6; mkp = mk6; }                              \
      PIN_E                                                          \
      float pm = wave_max63(p);                                      \
      int ee   = (__float_as_int(pm) >> 23) - 126;  /* pm=m*2^ee */  \
      float c  = __int_as_float((127 - ee) << 23);  /* 2^-ee exact */\
      k2 += (float)ee;                                               \
      float pn = dppmovf<0xB1, 0xF>(p);                              \
      __half2 pp = __floats2half2_rn(p, pn);                         \
      __half2 a0 = __float2half2_rn(0.f), a1 = a0, a2 = a0, a3 = a0; \
      FVG(0, E0,  E1,  E2,  E3,  E4,  E5)                            \
      FVG(1, E6,  E7,  E8,  E9,  E10, E11)                           \
      FVG(2, E12, E13, E14, E15, E16, E17)                           \
      FVG(3, E18, E19, E20, E21, E22, E23)                           \
      a0 = __hadd2(a0, a1); a2 = __hadd2(a2, a3); a0 = __hadd2(a0, a2); \
      float accF  = __low2float(a0) + __high2float(a0);              \
      float expem = EXP2F(e1 * L2E);                                 \
      float t  = accF * expem * c;                                   \
      float pc = p * c;                                              \
      p = fminf(fmaf(mk1, t - pc, pc), 1024.0f);                     \
      SHIFT_REGS }

#pragma unroll 6
    for (int s = 1; s <= 504; ++s) FV_STEP(true)
    FV_STEP(true)                          // s = 505 (loads row 511)
    FV_STEP(false) FV_STEP(false) FV_STEP(false)   // s = 506..508
    FV_STEP(false) FV_STEP(false) FV_STEP(false)   // s = 509..511

    float q = p * EXP2F(stopT[ri] * L2E);
    q = (i < T_DIM) ? q : 0.f;             // zero clone lanes
    float Sq = wave_sum63(q);
    float alpha = LN2 * (k2 + LOG2F(Sq));
    if (i == 0) out[1 + B_DIM + b] = alpha;
  } else {
    // ---- viterbi chain (max-plus), stale-max rebase every 8 steps ----
#define DECL_T(nn) __half2 T##nn = __floats2half2_rn( \
      trans[ri * T_DIM + 2*(nn)], trans[ri * T_DIM + 2*(nn) + 1]);
    DECL_T(0)  DECL_T(1)  DECL_T(2)  DECL_T(3)  DECL_T(4)  DECL_T(5)
    DECL_T(6)  DECL_T(7)  DECL_T(8)  DECL_T(9)  DECL_T(10) DECL_T(11)
    DECL_T(12) DECL_T(13) DECL_T(14) DECL_T(15) DECL_T(16) DECL_T(17)
    DECL_T(18) DECL_T(19) DECL_T(20) DECL_T(21) DECL_T(22) DECL_T(23)

#define PIN_T asm("" : "+v"(T0), "+v"(T1), "+v"(T2), "+v"(T3),       \
      "+v"(T4), "+v"(T5), "+v"(T6), "+v"(T7), "+v"(T8), "+v"(T9),    \
      "+v"(T10), "+v"(T11), "+v"(T12), "+v"(T13), "+v"(T14),         \
      "+v"(T15), "+v"(T16), "+v"(T17), "+v"(T18), "+v"(T19),         \
      "+v"(T20), "+v"(T21), "+v"(T22), "+v"(T23));

    float v = startT[ri] + emb[0];
    const __half2 NEGI = __floats2half2_rn(-60000.f, -60000.f);
    float m_ref = wave_max63(v);

#define VVG(g, Ta, Tb, Tc, Td, Te, Tf)                 \
    { __half2 t0 = bpick(vp, 12*(g) + 0);              \
      __half2 t1 = bpick(vp, 12*(g) + 2);              \
      __half2 t2 = bpick(vp, 12*(g) + 4);              \
      __half2 t3 = bpick(vp, 12*(g) + 6);              \
      __half2 t4 = bpick(vp, 12*(g) + 8);              \
      __half2 t5 = bpick(vp, 12*(g) + 10);             \
      m0 = hmax2(m0, __hadd2(t0, Ta));                 \
      m1 = hmax2(m1, __hadd2(t1, Tb));                 \
      m2 = hmax2(m2, __hadd2(t2, Tc));                 \
      m3 = hmax2(m3, __hadd2(t3, Td));                 \
      m0 = hmax2(m0, __hadd2(t4, Te));                 \
      m1 = hmax2(m1, __hadd2(t5, Tf)); }

#define VV_STEP(LOAD, DOTREE)                                        \
    { float ep, mkp;                                                 \
      if (LOAD) { ep = *pf; pf += estep; mkp = *pmk; pmk += B_DIM; } \
      else      { ep = e6; mkp = mk6; }                              \
      PIN_T                                                          \
      if (DOTREE) m_ref = wave_max63(v);                             \
      float vr  = v - m_ref;                                         \
      float vn_ = dppmovf<0xB1, 0xF>(vr);                            \
      __half2 vp = __floats2half2_rn(vr, vn_);                       \
      __half2 m0 = NEGI, m1 = NEGI, m2 = NEGI, m3 = NEGI;            \
      VVG(0, T0,  T1,  T2,  T3,  T4,  T5)                            \
      VVG(1, T6,  T7,  T8,  T9,  T10, T11)                           \
      VVG(2, T12, T13, T14, T15, T16, T17)                           \
      VVG(3, T18, T19, T20, T21, T22, T23)                           \
      m0 = hmax2(hmax2(m0, m1), hmax2(m2, m3));                      \
      float mx = fmaxf(__low2float(m0), __high2float(m0));           \
      float vnew = e1 + m_ref + mx;                                  \
      v = fmaf(mk1, vnew - v, v);                                    \
      SHIFT_REGS }

#pragma unroll 8
    for (int s = 1; s <= 504; ++s) VV_STEP(true, ((s & 7) == 0))
    VV_STEP(true, false)                   // s = 505 (loads row 511)
    VV_STEP(false, false) VV_STEP(false, false) VV_STEP(false, false)
    VV_STEP(false, false) VV_STEP(false, false) VV_STEP(false, false)

    float best = wave_max63(v + stopT[ri]);
    if (i == 0) out[1 + 2 * B_DIM + b] = best;
  }
}

// ---- loss = mean(alpha - real) ----
__global__ __launch_bounds__(256)
void crf_loss(float* __restrict__ out)
{
  __shared__ float red[256];
  int t = threadIdx.x;
  float a = 0.f;
  for (int b = t; b < B_DIM; b += 256)
    a += out[1 + B_DIM + b] - out[1 + b];
  red[t] = a;
  __syncthreads();
  for (int w = 128; w > 0; w >>= 1) {
    if (t < w) red[t] += red[t + w];
    __syncthreads();
  }
  if (t == 0) out[0] = red[0] * (1.0f / B_DIM);
}

extern "C" void kernel_launch(void* const* d_in, const int* in_sizes, int n_in,
                              void* d_out, int out_size, void* d_ws, size_t ws_size,
                              hipStream_t stream) {
  (void)in_sizes; (void)n_in; (void)d_ws; (void)ws_size; (void)out_size;
  const float* em     = (const float*)d_in[0];
  const int*   tags   = (const int*)d_in[1];
  const float* mask   = (const float*)d_in[2];
  const float* trans  = (const float*)d_in[3];
  const float* startT = (const float*)d_in[4];
  const float* stopT  = (const float*)d_in[5];
  float* out = (float*)d_out;

  hipLaunchKernelGGL(crf_fused, dim3(B_DIM), dim3(192), 0, stream,
                     em, tags, mask, trans, startT, stopT, out);
  hipLaunchKernelGGL(crf_loss, dim3(1), dim3(256), 0, stream, out);
}